// Round 1
// baseline (454.977 us; speedup 1.0000x reference)
//
#include <hip/hip_runtime.h>
#include <cstdint>

typedef float f32x4 __attribute__((ext_vector_type(4)));
typedef short bf16x8 __attribute__((ext_vector_type(8)));
typedef unsigned short u16x4 __attribute__((ext_vector_type(4)));

#define LOG2E 1.44269504088896340736f

#if __has_builtin(__builtin_amdgcn_exp2f)
#define EXP2(v) __builtin_amdgcn_exp2f(v)
#else
#define EXP2(v) exp2f(v)
#endif

// workspace byte offsets (all 16B-aligned)
enum : unsigned {
    WALL_OFF  = 0u,          // 192*256 bf16 (f rows pre-scaled by log2e)
    BALL_OFF  = 98304u,      // 192 f32 combined bias
    WV_OFF    = 99072u,      // 256*128 bf16
    FT_OFF    = 164608u,     // 8*4096*32 bf16, layout [b][n][k]
    GT_OFF    = 2261760u,    // 8*4096*32 bf16, layout [b][m][k]
    H_OFF     = 4358912u,    // 8*128*4096 bf16, layout [b][c][n]
    SCALE_OFF = 12747520u,   // 8*4096 f32: 1/Z[n]
};

static __device__ __forceinline__ unsigned short f2bf(float f) {
    unsigned u = __builtin_bit_cast(unsigned, f);
    u += 0x7fffu + ((u >> 16) & 1u);   // RNE
    return (unsigned short)(u >> 16);
}

static __device__ __forceinline__ f32x4 mfma_bf16(bf16x8 a, bf16x8 b, f32x4 c) {
    return __builtin_amdgcn_mfma_f32_16x16x32_bf16(a, b, c, 0, 0, 0);
}

// ---- k0: pack weights to bf16 into workspace ----
__global__ __launch_bounds__(256) void k0_pack(const float* __restrict__ wf,
                                               const float* __restrict__ bfv,
                                               const float* __restrict__ wg,
                                               const float* __restrict__ bg,
                                               const float* __restrict__ wh,
                                               const float* __restrict__ bh,
                                               const float* __restrict__ wv,
                                               unsigned char* __restrict__ ws) {
    unsigned idx = blockIdx.x * 256u + threadIdx.x;
    unsigned short* Wall = (unsigned short*)(ws + WALL_OFF);
    float* ball = (float*)(ws + BALL_OFF);
    unsigned short* wvb = (unsigned short*)(ws + WV_OFF);
    if (idx < 49152u) {                    // Wall[k][c], k in [0,192)
        unsigned k = idx >> 8;
        float v;
        if (k < 32u)      v = wf[idx] * LOG2E;
        else if (k < 64u) v = wg[idx - 8192u];
        else              v = wh[idx - 16384u];
        Wall[idx] = f2bf(v);
    } else if (idx < 49344u) {             // ball[192]
        unsigned k = idx - 49152u;
        float v;
        if (k < 32u)      v = bfv[k] * LOG2E;
        else if (k < 64u) v = bg[k - 32u];
        else              v = bh[k - 64u];
        ball[k] = v;
    } else if (idx < 82112u) {             // wv bf16 copy [cc][c] row-major
        unsigned j = idx - 49344u;
        wvb[j] = f2bf(wv[j]);
    }
}

// ---- k1: projections P = Wall(192x256) @ X_b(256x4096) + bias ----
// writes Ft[b][n][k0..31], Gt[b][m][k0..31], H[b][c][n]
__global__ __launch_bounds__(256) void k1_proj(const float* __restrict__ x,
                                               unsigned char* __restrict__ ws) {
    __shared__ unsigned short Xt[64 * 264];   // [n][c] bf16, padded
    const int b = blockIdx.y;
    const int n0 = blockIdx.x * 64;
    const unsigned short* Wall = (const unsigned short*)(ws + WALL_OFF);
    const float* ball = (const float*)(ws + BALL_OFF);
    unsigned short* Ft = (unsigned short*)(ws + FT_OFF) + b * (4096 * 32);
    unsigned short* Gt = (unsigned short*)(ws + GT_OFF) + b * (4096 * 32);
    unsigned short* Hm = (unsigned short*)(ws + H_OFF) + b * (128 * 4096);
    const float* xb = x + b * (256 * 4096) + n0;
    const int tid = threadIdx.x;
    #pragma unroll 4
    for (int i = 0; i < 64; ++i) {
        int idx = i * 256 + tid;
        int c = idx >> 6, n = idx & 63;
        Xt[n * 264 + c] = f2bf(xb[c * 4096 + n]);
    }
    __syncthreads();
    const int lane = tid & 63, l15 = tid & 15, quad = lane >> 4, w = tid >> 6;
    bf16x8 bX[8];
    #pragma unroll
    for (int ks = 0; ks < 8; ++ks)
        bX[ks] = *(const bf16x8*)&Xt[(w * 16 + l15) * 264 + ks * 32 + quad * 8];
    const int ncol = n0 + w * 16 + l15;
    #pragma unroll
    for (int kt = 0; kt < 12; ++kt) {
        f32x4 acc = {0.f, 0.f, 0.f, 0.f};
        #pragma unroll
        for (int ks = 0; ks < 8; ++ks) {
            bf16x8 aW = *(const bf16x8*)&Wall[(kt * 16 + l15) * 256 + ks * 32 + quad * 8];
            acc = mfma_bf16(aW, bX[ks], acc);
        }
        const int kr0 = kt * 16 + quad * 4;   // D row = quad*4+r, col = l15
        #pragma unroll
        for (int r = 0; r < 4; ++r) acc[r] += ball[kr0 + r];
        if (kt < 4) {
            u16x4 pk;
            #pragma unroll
            for (int r = 0; r < 4; ++r) pk[r] = f2bf(acc[r]);
            unsigned short* dst = (kt < 2) ? Ft : Gt;
            int kk = ((kt & 1) * 16) + quad * 4;
            *(u16x4*)&dst[ncol * 32 + kk] = pk;
        } else {
            #pragma unroll
            for (int r = 0; r < 4; ++r)
                Hm[(kr0 - 64 + r) * 4096 + ncol] = f2bf(acc[r]);
        }
    }
}

// ---- k2: pass A — scale[b][n] = 1 / sum_m exp2(s'[n][m]) ----
__global__ __launch_bounds__(256) void k2_stats(unsigned char* __restrict__ ws) {
    const int b = blockIdx.y;
    const unsigned short* Ft = (const unsigned short*)(ws + FT_OFF) + b * (4096 * 32);
    const unsigned short* Gt = (const unsigned short*)(ws + GT_OFF) + b * (4096 * 32);
    float* scale = (float*)(ws + SCALE_OFF) + b * 4096;
    const int tid = threadIdx.x;
    const int lane = tid & 63, l15 = tid & 15, quad = lane >> 4, w = tid >> 6;
    const int n0 = blockIdx.x * 64 + w * 16;
    const bf16x8 aF = *(const bf16x8*)&Ft[(n0 + l15) * 32 + quad * 8];
    f32x4 z = {0.f, 0.f, 0.f, 0.f};
    #pragma unroll 2
    for (int mt = 0; mt < 256; ++mt) {
        bf16x8 bG = *(const bf16x8*)&Gt[(mt * 16 + l15) * 32 + quad * 8];
        f32x4 s = mfma_bf16(aF, bG, (f32x4){0.f, 0.f, 0.f, 0.f});
        #pragma unroll
        for (int r = 0; r < 4; ++r)
            z[r] += EXP2(fminf(s[r], 100.f));
    }
    #pragma unroll
    for (int off = 1; off < 16; off <<= 1) {
        #pragma unroll
        for (int r = 0; r < 4; ++r) z[r] += __shfl_xor(z[r], off, 64);
    }
    if (l15 == 0) {
        #pragma unroll
        for (int r = 0; r < 4; ++r)
            scale[n0 + quad * 4 + r] = 1.f / z[r];
    }
}

// ---- k3: pass B — O[c][m] = sum_n H[c][n]*exp2(s')*scale[n]; fused out proj ----
__global__ __launch_bounds__(256) void k3_attn(const float* __restrict__ x,
                                               const float* __restrict__ bv,
                                               const float* __restrict__ gamma,
                                               float* __restrict__ out,
                                               unsigned char* __restrict__ ws) {
    __shared__ float sc_lds[4096];
    __shared__ unsigned short E[4][16][40];   // per-wave private [m local][n], padded
    __shared__ unsigned short O[64][136];     // [m][c] bf16, padded
    const int b = blockIdx.y;
    const int tid = threadIdx.x;
    const int lane = tid & 63, l15 = tid & 15, quad = lane >> 4, w = tid >> 6;
    const unsigned short* Ft = (const unsigned short*)(ws + FT_OFF) + b * (4096 * 32);
    const unsigned short* Gt = (const unsigned short*)(ws + GT_OFF) + b * (4096 * 32);
    const unsigned short* Hm = (const unsigned short*)(ws + H_OFF) + b * (128 * 4096);
    const float* scale = (const float*)(ws + SCALE_OFF) + b * 4096;
    #pragma unroll
    for (int i = 0; i < 4; ++i) {
        int idx = (i * 256 + tid) * 4;
        *(f32x4*)&sc_lds[idx] = *(const f32x4*)&scale[idx];
    }
    __syncthreads();
    const int m0 = blockIdx.x * 64 + w * 16;
    const bf16x8 bG = *(const bf16x8*)&Gt[(m0 + l15) * 32 + quad * 8];
    f32x4 acc[8];
    #pragma unroll
    for (int ct = 0; ct < 8; ++ct) acc[ct] = (f32x4){0.f, 0.f, 0.f, 0.f};
    for (int ns = 0; ns < 128; ++ns) {
        const int nb = ns * 32;
        bf16x8 aF0 = *(const bf16x8*)&Ft[(nb + l15) * 32 + quad * 8];
        bf16x8 aF1 = *(const bf16x8*)&Ft[(nb + 16 + l15) * 32 + quad * 8];
        f32x4 s0 = mfma_bf16(aF0, bG, (f32x4){0.f, 0.f, 0.f, 0.f});
        f32x4 s1 = mfma_bf16(aF1, bG, (f32x4){0.f, 0.f, 0.f, 0.f});
        f32x4 c0 = *(const f32x4*)&sc_lds[nb + quad * 4];
        f32x4 c1 = *(const f32x4*)&sc_lds[nb + 16 + quad * 4];
        u16x4 e0, e1;
        #pragma unroll
        for (int r = 0; r < 4; ++r) {
            e0[r] = f2bf(EXP2(fminf(s0[r], 100.f)) * c0[r]);
            e1[r] = f2bf(EXP2(fminf(s1[r], 100.f)) * c1[r]);
        }
        // C-layout (n = quad*4+r consecutive) -> LDS [m][n]; wave-private rows
        *(u16x4*)&E[w][l15][quad * 4] = e0;
        *(u16x4*)&E[w][l15][16 + quad * 4] = e1;
        __asm__ __volatile__("s_waitcnt lgkmcnt(0)" ::: "memory");
        bf16x8 bE = *(const bf16x8*)&E[w][l15][quad * 8];
        #pragma unroll
        for (int ct = 0; ct < 8; ++ct) {
            bf16x8 aH = *(const bf16x8*)&Hm[(ct * 16 + l15) * 4096 + nb + quad * 8];
            acc[ct] = mfma_bf16(aH, bE, acc[ct]);
        }
    }
    // epilogue: O tile -> LDS, then out = x + gamma*(Wv @ O + bv)
    #pragma unroll
    for (int ct = 0; ct < 8; ++ct) {
        u16x4 pk;
        #pragma unroll
        for (int r = 0; r < 4; ++r) pk[r] = f2bf(acc[ct][r]);
        *(u16x4*)&O[w * 16 + l15][ct * 16 + quad * 4] = pk;
    }
    __syncthreads();
    const unsigned short* Wv = (const unsigned short*)(ws + WV_OFF);
    const float gam = gamma[0];
    bf16x8 bO[4];
    #pragma unroll
    for (int ks = 0; ks < 4; ++ks)
        bO[ks] = *(const bf16x8*)&O[w * 16 + l15][ks * 32 + quad * 8];
    const float* xb = x + b * (256 * 4096);
    float* ob = out + b * (256 * 4096);
    const int m = blockIdx.x * 64 + w * 16 + l15;
    #pragma unroll
    for (int cct = 0; cct < 16; ++cct) {
        f32x4 f = {0.f, 0.f, 0.f, 0.f};
        #pragma unroll
        for (int ks = 0; ks < 4; ++ks) {
            bf16x8 aV = *(const bf16x8*)&Wv[(cct * 16 + l15) * 128 + ks * 32 + quad * 8];
            f = mfma_bf16(aV, bO[ks], f);
        }
        const int cc0 = cct * 16 + quad * 4;
        #pragma unroll
        for (int r = 0; r < 4; ++r) {
            const int cc = cc0 + r;
            ob[cc * 4096 + m] = xb[cc * 4096 + m] + gam * (f[r] + bv[cc]);
        }
    }
}

extern "C" void kernel_launch(void* const* d_in, const int* in_sizes, int n_in,
                              void* d_out, int out_size, void* d_ws, size_t ws_size,
                              hipStream_t stream) {
    const float* x   = (const float*)d_in[0];
    const float* wf  = (const float*)d_in[1];
    const float* bfv = (const float*)d_in[2];
    const float* wg  = (const float*)d_in[3];
    const float* bg  = (const float*)d_in[4];
    const float* wh  = (const float*)d_in[5];
    const float* bh  = (const float*)d_in[6];
    const float* wv  = (const float*)d_in[7];
    const float* bv  = (const float*)d_in[8];
    const float* gam = (const float*)d_in[9];
    float* out = (float*)d_out;
    unsigned char* ws = (unsigned char*)d_ws;
    (void)in_sizes; (void)n_in; (void)out_size; (void)ws_size;

    hipLaunchKernelGGL(k0_pack, dim3(321), dim3(256), 0, stream,
                       wf, bfv, wg, bg, wh, bh, wv, ws);
    hipLaunchKernelGGL(k1_proj, dim3(64, 8), dim3(256), 0, stream, x, ws);
    hipLaunchKernelGGL(k2_stats, dim3(64, 8), dim3(256), 0, stream, ws);
    hipLaunchKernelGGL(k3_attn, dim3(64, 8), dim3(256), 0, stream,
                       x, bv, gam, out, ws);
}

// Round 2
// 439.817 us; speedup vs baseline: 1.0345x; 1.0345x over previous
//
#include <hip/hip_runtime.h>
#include <cstdint>

typedef float f32x4 __attribute__((ext_vector_type(4)));
typedef short bf16x8 __attribute__((ext_vector_type(8)));
typedef unsigned short u16x4 __attribute__((ext_vector_type(4)));
typedef unsigned uint4v __attribute__((ext_vector_type(4)));
typedef unsigned uint2v __attribute__((ext_vector_type(2)));

#define LOG2E 1.44269504088896340736f

#if __has_builtin(__builtin_amdgcn_exp2f)
#define EXP2(v) __builtin_amdgcn_exp2f(v)
#else
#define EXP2(v) exp2f(v)
#endif

// workspace byte offsets (all 16B-aligned)
enum : unsigned {
    WALL_OFF  = 0u,          // 192*256 bf16 (f rows pre-scaled by log2e)
    BALL_OFF  = 98304u,      // 192 f32 combined bias
    WV_OFF    = 99072u,      // 256*128 bf16
    FT_OFF    = 164608u,     // 8*4096*32 bf16, layout [b][n][k]
    GT_OFF    = 2261760u,    // 8*4096*32 bf16, layout [b][m][k]
    H_OFF     = 4358912u,    // 8*128*4096 bf16, layout [b][c][n]
    SCALE_OFF = 12747520u,   // 8*4096 f32: 1/Z[n]
    ZPART_OFF = 12878592u,   // 4*8*4096 f32 partial Z sums
};

static __device__ __forceinline__ unsigned short f2bf(float f) {
    unsigned u = __builtin_bit_cast(unsigned, f);
    u += 0x7fffu + ((u >> 16) & 1u);   // RNE
    return (unsigned short)(u >> 16);
}

// pack two f32 -> packed bf16 pair (round-to-nearest, ties away): 2 adds + 1 v_perm
static __device__ __forceinline__ unsigned pk_bf(float lo, float hi) {
    unsigned a = __builtin_bit_cast(unsigned, hi) + 0x8000u;
    unsigned b = __builtin_bit_cast(unsigned, lo) + 0x8000u;
    return __builtin_amdgcn_perm(a, b, 0x07060302u);
}

static __device__ __forceinline__ f32x4 mfma_bf16(bf16x8 a, bf16x8 b, f32x4 c) {
    return __builtin_amdgcn_mfma_f32_16x16x32_bf16(a, b, c, 0, 0, 0);
}

// ---- k0: pack weights to bf16 into workspace ----
__global__ __launch_bounds__(256) void k0_pack(const float* __restrict__ wf,
                                               const float* __restrict__ bfv,
                                               const float* __restrict__ wg,
                                               const float* __restrict__ bg,
                                               const float* __restrict__ wh,
                                               const float* __restrict__ bh,
                                               const float* __restrict__ wv,
                                               unsigned char* __restrict__ ws) {
    unsigned idx = blockIdx.x * 256u + threadIdx.x;
    unsigned short* Wall = (unsigned short*)(ws + WALL_OFF);
    float* ball = (float*)(ws + BALL_OFF);
    unsigned short* wvb = (unsigned short*)(ws + WV_OFF);
    if (idx < 49152u) {                    // Wall[k][c], k in [0,192)
        unsigned k = idx >> 8;
        float v;
        if (k < 32u)      v = wf[idx] * LOG2E;
        else if (k < 64u) v = wg[idx - 8192u];
        else              v = wh[idx - 16384u];
        Wall[idx] = f2bf(v);
    } else if (idx < 49344u) {             // ball[192]
        unsigned k = idx - 49152u;
        float v;
        if (k < 32u)      v = bfv[k] * LOG2E;
        else if (k < 64u) v = bg[k - 32u];
        else              v = bh[k - 64u];
        ball[k] = v;
    } else if (idx < 82112u) {             // wv bf16 copy [cc][c] row-major
        unsigned j = idx - 49344u;
        wvb[j] = f2bf(wv[j]);
    }
}

// ---- k1: projections P = Wall(192x256) @ X_b(256x4096) + bias ----
// B-fragments of X^T built directly from global (no LDS, no bank conflicts)
__global__ __launch_bounds__(256) void k1_proj(const float* __restrict__ x,
                                               unsigned char* __restrict__ ws) {
    const int b = blockIdx.y;
    const int n0 = blockIdx.x * 64;
    const unsigned short* Wall = (const unsigned short*)(ws + WALL_OFF);
    const float* ball = (const float*)(ws + BALL_OFF);
    unsigned short* Ft = (unsigned short*)(ws + FT_OFF) + b * (4096 * 32);
    unsigned short* Gt = (unsigned short*)(ws + GT_OFF) + b * (4096 * 32);
    unsigned short* Hm = (unsigned short*)(ws + H_OFF) + b * (128 * 4096);
    const int tid = threadIdx.x;
    const int l = tid & 15, q = (tid >> 4) & 3, w = tid >> 6;
    const int ncol = n0 + w * 16 + l;
    const float* xb = x + b * (256 * 4096) + ncol;
    bf16x8 bX[8];
    #pragma unroll
    for (int ks = 0; ks < 8; ++ks) {
        uint4v rr;
        #pragma unroll
        for (int jp = 0; jp < 4; ++jp) {
            const int c = ks * 32 + q * 8 + jp * 2;
            rr[jp] = pk_bf(xb[c * 4096], xb[(c + 1) * 4096]);
        }
        bX[ks] = __builtin_bit_cast(bf16x8, rr);
    }
    #pragma unroll
    for (int kt = 0; kt < 12; ++kt) {
        f32x4 acc = {0.f, 0.f, 0.f, 0.f};
        #pragma unroll
        for (int ks = 0; ks < 8; ++ks) {
            bf16x8 aW = *(const bf16x8*)&Wall[(kt * 16 + l) * 256 + ks * 32 + q * 8];
            acc = mfma_bf16(aW, bX[ks], acc);
        }
        const int kr0 = kt * 16 + q * 4;   // D row = q*4+r, col = l
        #pragma unroll
        for (int r = 0; r < 4; ++r) acc[r] += ball[kr0 + r];
        if (kt < 4) {
            u16x4 pk;
            #pragma unroll
            for (int r = 0; r < 4; ++r) pk[r] = f2bf(acc[r]);
            unsigned short* dst = (kt < 2) ? Ft : Gt;
            int kk = ((kt & 1) * 16) + q * 4;
            *(u16x4*)&dst[ncol * 32 + kk] = pk;
        } else {
            #pragma unroll
            for (int r = 0; r < 4; ++r)
                Hm[(kr0 - 64 + r) * 4096 + ncol] = f2bf(acc[r]);
        }
    }
}

// ---- k2: pass A — partial Z[n] = sum over m-slice of exp2(s'[n][m]) ----
__global__ __launch_bounds__(256) void k2_stats(unsigned char* __restrict__ ws) {
    const int b = blockIdx.y, zsl = blockIdx.z;
    const unsigned short* Ft = (const unsigned short*)(ws + FT_OFF) + b * (4096 * 32);
    const unsigned short* Gt = (const unsigned short*)(ws + GT_OFF) + b * (4096 * 32);
    float* Zp = (float*)(ws + ZPART_OFF) + zsl * 32768 + b * 4096;
    const int tid = threadIdx.x;
    const int l = tid & 15, q = (tid >> 4) & 3, w = tid >> 6;
    const int n0 = blockIdx.x * 64 + w * 16;
    const bf16x8 aF = *(const bf16x8*)&Ft[(n0 + l) * 32 + q * 8];
    f32x4 z = {0.f, 0.f, 0.f, 0.f};
    const int mt0 = zsl * 64;
    #pragma unroll 4
    for (int mt = mt0; mt < mt0 + 64; ++mt) {
        bf16x8 bG = *(const bf16x8*)&Gt[(mt * 16 + l) * 32 + q * 8];
        f32x4 s = mfma_bf16(aF, bG, (f32x4){0.f, 0.f, 0.f, 0.f});
        #pragma unroll
        for (int r = 0; r < 4; ++r)
            z[r] += EXP2(fminf(s[r], 100.f));
    }
    #pragma unroll
    for (int off = 1; off < 16; off <<= 1) {
        #pragma unroll
        for (int r = 0; r < 4; ++r) z[r] += __shfl_xor(z[r], off, 64);
    }
    if (l == 0) {
        #pragma unroll
        for (int r = 0; r < 4; ++r)
            Zp[n0 + q * 4 + r] = z[r];
    }
}

// ---- k2b: scale = 1 / sum of 4 partials ----
__global__ __launch_bounds__(256) void k2b_inv(unsigned char* __restrict__ ws) {
    const float* zp = (const float*)(ws + ZPART_OFF);
    float* scale = (float*)(ws + SCALE_OFF);
    const int idx = (blockIdx.x * 256 + threadIdx.x) * 4;
    f32x4 s = *(const f32x4*)&zp[idx];
    s += *(const f32x4*)&zp[32768 + idx];
    s += *(const f32x4*)&zp[65536 + idx];
    s += *(const f32x4*)&zp[98304 + idx];
    f32x4 o;
    #pragma unroll
    for (int r = 0; r < 4; ++r) o[r] = 1.f / s[r];
    *(f32x4*)&scale[idx] = o;
}

// ---- k3: pass B — O[c][m] = sum_n H[c][n]*exp2(s')*scale[n]; fused out proj ----
// m-tile 32, n-loop split across wave pairs; C->B layout fix via 8 shfl (no LDS fence)
__global__ __launch_bounds__(256, 4) void k3_attn(const float* __restrict__ x,
                                                  const float* __restrict__ bv,
                                                  const float* __restrict__ gamma,
                                                  float* __restrict__ out,
                                                  unsigned char* __restrict__ ws) {
    __shared__ float OP[2][128][17];          // [msub][c][m-local] partial exchange
    __shared__ unsigned short Obf[32][136];   // [m][c] bf16
    const int b = blockIdx.y, tid = threadIdx.x;
    const int l = tid & 15, q = (tid >> 4) & 3, w = tid >> 6;
    const int msub = w & 1, nhalf = w >> 1;
    const unsigned short* Ft = (const unsigned short*)(ws + FT_OFF) + b * (4096 * 32);
    const unsigned short* Gt = (const unsigned short*)(ws + GT_OFF) + b * (4096 * 32);
    const unsigned short* Hm = (const unsigned short*)(ws + H_OFF) + b * (128 * 4096);
    const float* scale = (const float*)(ws + SCALE_OFF) + b * 4096;
    const int m0 = blockIdx.x * 32 + msub * 16;
    const bf16x8 bG = *(const bf16x8*)&Gt[(m0 + l) * 32 + q * 8];
    f32x4 acc[8];
    #pragma unroll
    for (int ct = 0; ct < 8; ++ct) acc[ct] = (f32x4){0.f, 0.f, 0.f, 0.f};
    const int nbase = nhalf * 2048;
    bf16x8 aF0 = *(const bf16x8*)&Ft[(nbase + l) * 32 + q * 8];
    bf16x8 aF1 = *(const bf16x8*)&Ft[(nbase + 16 + l) * 32 + q * 8];
    f32x4 c0 = *(const f32x4*)&scale[nbase + q * 4];
    f32x4 c1 = *(const f32x4*)&scale[nbase + 16 + q * 4];
    const bool qlo = q < 2;
    const int srcA = (q & 1) * 32 + l;
    const int srcB = srcA + 16;
    for (int i = 0; i < 64; ++i) {
        const int nb = nbase + i * 32;
        const bf16x8 f0 = aF0, f1 = aF1;
        const f32x4 s0c = c0, s1c = c1;
        const int nbn = nbase + ((i + 1) & 63) * 32;   // wraps on last iter (unused)
        aF0 = *(const bf16x8*)&Ft[(nbn + l) * 32 + q * 8];
        aF1 = *(const bf16x8*)&Ft[(nbn + 16 + l) * 32 + q * 8];
        c0 = *(const f32x4*)&scale[nbn + q * 4];
        c1 = *(const f32x4*)&scale[nbn + 16 + q * 4];
        f32x4 s0 = mfma_bf16(f0, bG, (f32x4){0.f, 0.f, 0.f, 0.f});
        f32x4 s1 = mfma_bf16(f1, bG, (f32x4){0.f, 0.f, 0.f, 0.f});
        f32x4 e0, e1;
        #pragma unroll
        for (int r = 0; r < 4; ++r) {
            e0[r] = EXP2(fminf(s0[r], 100.f)) * s0c[r];
            e1[r] = EXP2(fminf(s1[r], 100.f)) * s1c[r];
        }
        const unsigned a01 = pk_bf(e0[0], e0[1]), a23 = pk_bf(e0[2], e0[3]);
        const unsigned b01 = pk_bf(e1[0], e1[1]), b23 = pk_bf(e1[2], e1[3]);
        uint4v rr;
        {
            int tA = __shfl((int)a01, srcA, 64), tB = __shfl((int)b01, srcA, 64);
            rr[0] = (unsigned)(qlo ? tA : tB);
            tA = __shfl((int)a23, srcA, 64); tB = __shfl((int)b23, srcA, 64);
            rr[1] = (unsigned)(qlo ? tA : tB);
            tA = __shfl((int)a01, srcB, 64); tB = __shfl((int)b01, srcB, 64);
            rr[2] = (unsigned)(qlo ? tA : tB);
            tA = __shfl((int)a23, srcB, 64); tB = __shfl((int)b23, srcB, 64);
            rr[3] = (unsigned)(qlo ? tA : tB);
        }
        const bf16x8 bE = __builtin_bit_cast(bf16x8, rr);
        #pragma unroll
        for (int ct = 0; ct < 8; ++ct) {
            bf16x8 aH = *(const bf16x8*)&Hm[(ct * 16 + l) * 4096 + nb + q * 8];
            acc[ct] = mfma_bf16(aH, bE, acc[ct]);
        }
    }
    // combine n-halves through LDS
    if (nhalf) {
        #pragma unroll
        for (int ct = 0; ct < 8; ++ct)
            #pragma unroll
            for (int r = 0; r < 4; ++r)
                OP[msub][ct * 16 + q * 4 + r][l] = acc[ct][r];
    }
    __syncthreads();
    if (!nhalf) {
        #pragma unroll
        for (int ct = 0; ct < 8; ++ct) {
            #pragma unroll
            for (int r = 0; r < 4; ++r)
                acc[ct][r] += OP[msub][ct * 16 + q * 4 + r][l];
            uint2v p;
            p[0] = pk_bf(acc[ct][0], acc[ct][1]);
            p[1] = pk_bf(acc[ct][2], acc[ct][3]);
            *(uint2v*)&Obf[msub * 16 + l][ct * 16 + q * 4] = p;
        }
    }
    __syncthreads();
    // epilogue: out = x + gamma*(Wv @ O + bv); wave w: m-sub w&1, ct range (w>>1)*8
    const unsigned short* Wv = (const unsigned short*)(ws + WV_OFF);
    const float gam = gamma[0];
    const int msube = w & 1, ctbase = (w >> 1) * 8;
    bf16x8 bO[4];
    #pragma unroll
    for (int ks = 0; ks < 4; ++ks)
        bO[ks] = *(const bf16x8*)&Obf[msube * 16 + l][ks * 32 + q * 8];
    const int mg = blockIdx.x * 32 + msube * 16 + l;
    const float* xb = x + b * (256 * 4096);
    float* ob = out + b * (256 * 4096);
    #pragma unroll
    for (int t = 0; t < 8; ++t) {
        const int cct = ctbase + t;
        f32x4 f = {0.f, 0.f, 0.f, 0.f};
        #pragma unroll
        for (int ks = 0; ks < 4; ++ks) {
            bf16x8 aV = *(const bf16x8*)&Wv[(cct * 16 + l) * 128 + ks * 32 + q * 8];
            f = mfma_bf16(aV, bO[ks], f);
        }
        const int cc0 = cct * 16 + q * 4;
        #pragma unroll
        for (int r = 0; r < 4; ++r) {
            const int cc = cc0 + r;
            ob[cc * 4096 + mg] = xb[cc * 4096 + mg] + gam * (f[r] + bv[cc]);
        }
    }
}

extern "C" void kernel_launch(void* const* d_in, const int* in_sizes, int n_in,
                              void* d_out, int out_size, void* d_ws, size_t ws_size,
                              hipStream_t stream) {
    const float* x   = (const float*)d_in[0];
    const float* wf  = (const float*)d_in[1];
    const float* bfv = (const float*)d_in[2];
    const float* wg  = (const float*)d_in[3];
    const float* bg  = (const float*)d_in[4];
    const float* wh  = (const float*)d_in[5];
    const float* bh  = (const float*)d_in[6];
    const float* wv  = (const float*)d_in[7];
    const float* bv  = (const float*)d_in[8];
    const float* gam = (const float*)d_in[9];
    float* out = (float*)d_out;
    unsigned char* ws = (unsigned char*)d_ws;
    (void)in_sizes; (void)n_in; (void)out_size; (void)ws_size;

    hipLaunchKernelGGL(k0_pack, dim3(321), dim3(256), 0, stream,
                       wf, bfv, wg, bg, wh, bh, wv, ws);
    hipLaunchKernelGGL(k1_proj, dim3(64, 8), dim3(256), 0, stream, x, ws);
    hipLaunchKernelGGL(k2_stats, dim3(64, 8, 4), dim3(256), 0, stream, ws);
    hipLaunchKernelGGL(k2b_inv, dim3(32), dim3(256), 0, stream, ws);
    hipLaunchKernelGGL(k3_attn, dim3(128, 8), dim3(256), 0, stream,
                       x, bv, gam, out, ws);
}

// Round 3
// 276.337 us; speedup vs baseline: 1.6465x; 1.5916x over previous
//
#include <hip/hip_runtime.h>
#include <cstdint>

typedef float f32x4 __attribute__((ext_vector_type(4)));
typedef short bf16x8 __attribute__((ext_vector_type(8)));
typedef unsigned short u16x4 __attribute__((ext_vector_type(4)));
typedef unsigned uint4v __attribute__((ext_vector_type(4)));
typedef unsigned uint2v __attribute__((ext_vector_type(2)));

#define LOG2E 1.44269504088896340736f

#if __has_builtin(__builtin_amdgcn_exp2f)
#define EXP2(v) __builtin_amdgcn_exp2f(v)
#else
#define EXP2(v) exp2f(v)
#endif

// async global->LDS, 16B per lane, dest = wave-uniform base + lane*16
#define GLD16(gp, lp) __builtin_amdgcn_global_load_lds( \
    (const __attribute__((address_space(1))) unsigned*)(const void*)(gp), \
    (__attribute__((address_space(3))) unsigned*)(void*)(lp), 16, 0, 0)

// workspace byte offsets (all 16B-aligned)
enum : unsigned {
    WALL_OFF  = 0u,          // 192*256 bf16 (f rows pre-scaled by log2e)
    BALL_OFF  = 98304u,      // 192 f32 combined bias
    WVF_OFF   = 99072u,      // 256*128 bf16, fragment-major [cct][ks][lane][8]
    FF_OFF    = 164608u,     // 8*4096*32 bf16, frag-major [b][nt][lane][8]
    GF_OFF    = 2261760u,    // 8*4096*32 bf16, frag-major [b][mt][lane][8]
    HF_OFF    = 4358912u,    // 8*128*4096 bf16, frag-major [b][nt32][ct][lane][8]
    SCALE_OFF = 12747520u,   // 8*4096 f32: 1/Z[n]
    ZPART_OFF = 12878592u,   // 4*8*4096 f32 partial Z sums
};

static __device__ __forceinline__ unsigned short f2bf(float f) {
    unsigned u = __builtin_bit_cast(unsigned, f);
    u += 0x7fffu + ((u >> 16) & 1u);   // RNE
    return (unsigned short)(u >> 16);
}

// pack two f32 -> packed bf16 pair (round-to-nearest): 2 adds + 1 v_perm
static __device__ __forceinline__ unsigned pk_bf(float lo, float hi) {
    unsigned a = __builtin_bit_cast(unsigned, hi) + 0x8000u;
    unsigned b = __builtin_bit_cast(unsigned, lo) + 0x8000u;
    return __builtin_amdgcn_perm(a, b, 0x07060302u);
}

static __device__ __forceinline__ f32x4 mfma_bf16(bf16x8 a, bf16x8 b, f32x4 c) {
    return __builtin_amdgcn_mfma_f32_16x16x32_bf16(a, b, c, 0, 0, 0);
}

// ---- k0: pack weights to bf16 into workspace ----
__global__ __launch_bounds__(256) void k0_pack(const float* __restrict__ wf,
                                               const float* __restrict__ bfv,
                                               const float* __restrict__ wg,
                                               const float* __restrict__ bg,
                                               const float* __restrict__ wh,
                                               const float* __restrict__ bh,
                                               const float* __restrict__ wv,
                                               unsigned char* __restrict__ ws) {
    unsigned idx = blockIdx.x * 256u + threadIdx.x;
    unsigned short* Wall = (unsigned short*)(ws + WALL_OFF);
    float* ball = (float*)(ws + BALL_OFF);
    unsigned short* wvf = (unsigned short*)(ws + WVF_OFF);
    if (idx < 49152u) {                    // Wall[k][c], k in [0,192)
        unsigned k = idx >> 8;
        float v;
        if (k < 32u)      v = wf[idx] * LOG2E;
        else if (k < 64u) v = wg[idx - 8192u];
        else              v = wh[idx - 16384u];
        Wall[idx] = f2bf(v);
    } else if (idx < 49344u) {             // ball[192]
        unsigned k = idx - 49152u;
        float v;
        if (k < 32u)      v = bfv[k] * LOG2E;
        else if (k < 64u) v = bg[k - 32u];
        else              v = bh[k - 64u];
        ball[k] = v;
    } else if (idx < 82112u) {             // Wv -> fragment-major bf16
        unsigned jj = idx - 49344u;        // 0..32767, row-major [cc 256][c 128]
        unsigned cc = jj >> 7, c = jj & 127u;
        unsigned cct = cc >> 4, lv = cc & 15u;
        unsigned ksv = c >> 5, qv = (c >> 3) & 3u, jv = c & 7u;
        wvf[(((cct * 4u + ksv) * 4u + qv) * 16u + lv) * 8u + jv] = f2bf(wv[jj]);
    }
}

// ---- k1: projections P = Wall(192x256) @ X_b(256x4096) + bias ----
// writes Ff/Gf/Hf in fragment-major layouts
__global__ __launch_bounds__(256) void k1_proj(const float* __restrict__ x,
                                               unsigned char* __restrict__ ws) {
    const int b = blockIdx.y;
    const int n0 = blockIdx.x * 64;
    const unsigned short* Wall = (const unsigned short*)(ws + WALL_OFF);
    const float* ball = (const float*)(ws + BALL_OFF);
    unsigned short* Ff = (unsigned short*)(ws + FF_OFF) + b * 131072;
    unsigned short* Gf = (unsigned short*)(ws + GF_OFF) + b * 131072;
    unsigned short* Hf = (unsigned short*)(ws + HF_OFF) + b * 524288;
    const int tid = threadIdx.x;
    const int l = tid & 15, q = (tid >> 4) & 3, w = tid >> 6;
    const int ncol = n0 + w * 16 + l;
    const float* xb = x + b * (256 * 4096) + ncol;
    bf16x8 bX[8];
    #pragma unroll
    for (int ks = 0; ks < 8; ++ks) {
        uint4v rr;
        #pragma unroll
        for (int jp = 0; jp < 4; ++jp) {
            const int c = ks * 32 + q * 8 + jp * 2;
            rr[jp] = pk_bf(xb[c * 4096], xb[(c + 1) * 4096]);
        }
        bX[ks] = __builtin_bit_cast(bf16x8, rr);
    }
    #pragma unroll
    for (int kt = 0; kt < 12; ++kt) {
        f32x4 acc = {0.f, 0.f, 0.f, 0.f};
        #pragma unroll
        for (int ks = 0; ks < 8; ++ks) {
            bf16x8 aW = *(const bf16x8*)&Wall[(kt * 16 + l) * 256 + ks * 32 + q * 8];
            acc = mfma_bf16(aW, bX[ks], acc);
        }
        const int kr0 = kt * 16 + q * 4;   // D: row k = q*4+r, col = l
        #pragma unroll
        for (int r = 0; r < 4; ++r) acc[r] += ball[kr0 + r];
        if (kt < 4) {
            // F (kt 0,1) / G (kt 2,3), k within 32 = (kt&1)*16 + q*4 + r
            const int kk = kt & 1;
            unsigned short* dst = (kt < 2) ? Ff : Gf;
            const int nt = ncol >> 4;
            const int qf = kk * 2 + (q >> 1), j0 = (q & 1) * 4;
            u16x4 pk;
            #pragma unroll
            for (int r = 0; r < 4; ++r) pk[r] = f2bf(acc[r]);
            *(u16x4*)&dst[(nt * 64 + qf * 16 + l) * 8 + j0] = pk;
        } else {
            // H: c = (kt-4)*16 + q*4 + r, n = ncol
            const int ct = kt - 4;
            const int nt = ncol >> 5, qh = (ncol >> 3) & 3, jh = ncol & 7;
            #pragma unroll
            for (int r = 0; r < 4; ++r)
                Hf[((nt * 8 + ct) * 64 + qh * 16 + (q * 4 + r)) * 8 + jh] = f2bf(acc[r]);
        }
    }
}

// ---- k2: pass A — partial Z[n] over m-slice; wave owns n-sub 64 ----
__global__ __launch_bounds__(256) void k2_stats(unsigned char* __restrict__ ws) {
    const int b = blockIdx.y, zsl = blockIdx.z, tid = threadIdx.x;
    const int lane = tid & 63, l = tid & 15, q = (tid >> 4) & 3, w = tid >> 6;
    const unsigned short* Ff = (const unsigned short*)(ws + FF_OFF) + b * 131072;
    const unsigned short* Gf = (const unsigned short*)(ws + GF_OFF) + b * 131072;
    float* Zp = (float*)(ws + ZPART_OFF) + zsl * 32768 + b * 4096;
    const int n0 = blockIdx.x * 256 + w * 64;
    const int nt0 = n0 >> 4;
    bf16x8 aF[4];
    #pragma unroll
    for (int t = 0; t < 4; ++t)
        aF[t] = *(const bf16x8*)&Ff[((nt0 + t) * 64 + lane) * 8];
    f32x4 z[4];
    #pragma unroll
    for (int t = 0; t < 4; ++t) z[t] = (f32x4){0.f, 0.f, 0.f, 0.f};
    const int mt0 = zsl * 64;
    bf16x8 bG = *(const bf16x8*)&Gf[(mt0 * 64 + lane) * 8];
    for (int mt = 0; mt < 64; ++mt) {
        const bf16x8 g = bG;
        if (mt + 1 < 64)
            bG = *(const bf16x8*)&Gf[((mt0 + mt + 1) * 64 + lane) * 8];
        #pragma unroll
        for (int t = 0; t < 4; ++t) {
            f32x4 s = mfma_bf16(aF[t], g, (f32x4){0.f, 0.f, 0.f, 0.f});
            #pragma unroll
            for (int r = 0; r < 4; ++r)
                z[t][r] += EXP2(fminf(s[r], 100.f));
        }
    }
    #pragma unroll
    for (int off = 1; off < 16; off <<= 1)
        #pragma unroll
        for (int t = 0; t < 4; ++t)
            #pragma unroll
            for (int r = 0; r < 4; ++r)
                z[t][r] += __shfl_xor(z[t][r], off, 64);
    if (l == 0) {
        #pragma unroll
        for (int t = 0; t < 4; ++t)
            #pragma unroll
            for (int r = 0; r < 4; ++r)
                Zp[n0 + t * 16 + q * 4 + r] = z[t][r];
    }
}

// ---- k2b: scale = 1 / sum of 4 partials ----
__global__ __launch_bounds__(256) void k2b_inv(unsigned char* __restrict__ ws) {
    const float* zp = (const float*)(ws + ZPART_OFF);
    float* scale = (float*)(ws + SCALE_OFF);
    const int idx = (blockIdx.x * 256 + threadIdx.x) * 4;
    f32x4 s = *(const f32x4*)&zp[idx];
    s += *(const f32x4*)&zp[32768 + idx];
    s += *(const f32x4*)&zp[65536 + idx];
    s += *(const f32x4*)&zp[98304 + idx];
    f32x4 o;
    #pragma unroll
    for (int r = 0; r < 4; ++r) o[r] = 1.f / s[r];
    *(f32x4*)&scale[idx] = o;
}

// ---- k3: pass B — LDS-staged, double-buffered; m-tile 128, wave m-sub 32 ----
__global__ __launch_bounds__(256) void k3_attn(const float* __restrict__ x,
                                               const float* __restrict__ bv,
                                               const float* __restrict__ gamma,
                                               float* __restrict__ out,
                                               unsigned char* __restrict__ ws) {
    __shared__ __align__(16) unsigned short HT[2][4096];    // 8KB: 8 ct-frags
    __shared__ __align__(16) unsigned short FTs[2][1024];   // 2KB: 2 n-frags
    __shared__ __align__(16) unsigned short Obf[128][136];  // [m][c]
    const int b = blockIdx.y, tid = threadIdx.x;
    const int lane = tid & 63, l = tid & 15, q = (tid >> 4) & 3, w = tid >> 6;
    const unsigned short* Ff = (const unsigned short*)(ws + FF_OFF) + b * 131072;
    const unsigned short* Gf = (const unsigned short*)(ws + GF_OFF) + b * 131072;
    const unsigned short* Hf = (const unsigned short*)(ws + HF_OFF) + b * 524288;
    const float* scale = (const float*)(ws + SCALE_OFF) + b * 4096;
    const int mt0 = blockIdx.x * 8 + w * 2;      // wave's two m-frags
    const bf16x8 bG0 = *(const bf16x8*)&Gf[(mt0 * 64 + lane) * 8];
    const bf16x8 bG1 = *(const bf16x8*)&Gf[((mt0 + 1) * 64 + lane) * 8];
    f32x4 acc0[8], acc1[8];
    #pragma unroll
    for (int ct = 0; ct < 8; ++ct) {
        acc0[ct] = (f32x4){0.f, 0.f, 0.f, 0.f};
        acc1[ct] = (f32x4){0.f, 0.f, 0.f, 0.f};
    }
    const bool qlo = q < 2;
    const int srcA = (q & 1) * 32 + l;
    const int srcB = srcA + 16;

    // prologue stage of buffer 0 (tile i=0)
    {
        const unsigned short* Hg = Hf;
        GLD16(Hg + ((w * 2 + 0) * 64 + lane) * 8, &HT[0][(w * 2 + 0) * 512]);
        GLD16(Hg + ((w * 2 + 1) * 64 + lane) * 8, &HT[0][(w * 2 + 1) * 512]);
        if (w < 2)
            GLD16(Ff + ((size_t)w * 64 + lane) * 8, &FTs[0][w * 512]);
    }
    f32x4 c0 = *(const f32x4*)&scale[q * 4];
    f32x4 c1 = *(const f32x4*)&scale[16 + q * 4];

    for (int i = 0; i < 128; ++i) {
        const int p = i & 1;
        __syncthreads();   // drains stage(p) (vmcnt before barrier)
        if (i + 1 < 128) {
            const unsigned short* Hg = Hf + (size_t)(i + 1) * 4096;
            GLD16(Hg + ((w * 2 + 0) * 64 + lane) * 8, &HT[p ^ 1][(w * 2 + 0) * 512]);
            GLD16(Hg + ((w * 2 + 1) * 64 + lane) * 8, &HT[p ^ 1][(w * 2 + 1) * 512]);
            if (w < 2)
                GLD16(Ff + ((size_t)((i + 1) * 2 + w) * 64 + lane) * 8, &FTs[p ^ 1][w * 512]);
        }
        const int inx = (i + 1 < 128) ? (i + 1) : 127;
        f32x4 c0n = *(const f32x4*)&scale[inx * 32 + q * 4];
        f32x4 c1n = *(const f32x4*)&scale[inx * 32 + 16 + q * 4];
        const bf16x8 aF0 = *(const bf16x8*)&FTs[p][lane * 8];
        const bf16x8 aF1 = *(const bf16x8*)&FTs[p][512 + lane * 8];
        const f32x4 zz = {0.f, 0.f, 0.f, 0.f};
        f32x4 s0 = mfma_bf16(aF0, bG0, zz);
        f32x4 s1 = mfma_bf16(aF1, bG0, zz);
        f32x4 s2 = mfma_bf16(aF0, bG1, zz);
        f32x4 s3 = mfma_bf16(aF1, bG1, zz);
        f32x4 e0, e1, e2, e3;
        #pragma unroll
        for (int r = 0; r < 4; ++r) {
            e0[r] = EXP2(fminf(s0[r], 100.f)) * c0[r];
            e1[r] = EXP2(fminf(s1[r], 100.f)) * c1[r];
            e2[r] = EXP2(fminf(s2[r], 100.f)) * c0[r];
            e3[r] = EXP2(fminf(s3[r], 100.f)) * c1[r];
        }
        const unsigned a01 = pk_bf(e0[0], e0[1]), a23 = pk_bf(e0[2], e0[3]);
        const unsigned b01 = pk_bf(e1[0], e1[1]), b23 = pk_bf(e1[2], e1[3]);
        const unsigned g01 = pk_bf(e2[0], e2[1]), g23 = pk_bf(e2[2], e2[3]);
        const unsigned h01 = pk_bf(e3[0], e3[1]), h23 = pk_bf(e3[2], e3[3]);
        uint4v r0, r1;
        {
            int tA, tB;
            tA = __shfl((int)a01, srcA, 64); tB = __shfl((int)b01, srcA, 64);
            r0[0] = (unsigned)(qlo ? tA : tB);
            tA = __shfl((int)a23, srcA, 64); tB = __shfl((int)b23, srcA, 64);
            r0[1] = (unsigned)(qlo ? tA : tB);
            tA = __shfl((int)a01, srcB, 64); tB = __shfl((int)b01, srcB, 64);
            r0[2] = (unsigned)(qlo ? tA : tB);
            tA = __shfl((int)a23, srcB, 64); tB = __shfl((int)b23, srcB, 64);
            r0[3] = (unsigned)(qlo ? tA : tB);
            tA = __shfl((int)g01, srcA, 64); tB = __shfl((int)h01, srcA, 64);
            r1[0] = (unsigned)(qlo ? tA : tB);
            tA = __shfl((int)g23, srcA, 64); tB = __shfl((int)h23, srcA, 64);
            r1[1] = (unsigned)(qlo ? tA : tB);
            tA = __shfl((int)g01, srcB, 64); tB = __shfl((int)h01, srcB, 64);
            r1[2] = (unsigned)(qlo ? tA : tB);
            tA = __shfl((int)g23, srcB, 64); tB = __shfl((int)h23, srcB, 64);
            r1[3] = (unsigned)(qlo ? tA : tB);
        }
        const bf16x8 bE0 = __builtin_bit_cast(bf16x8, r0);
        const bf16x8 bE1 = __builtin_bit_cast(bf16x8, r1);
        #pragma unroll
        for (int ct = 0; ct < 8; ++ct) {
            const bf16x8 aH = *(const bf16x8*)&HT[p][ct * 512 + lane * 8];
            acc0[ct] = mfma_bf16(aH, bE0, acc0[ct]);
            acc1[ct] = mfma_bf16(aH, bE1, acc1[ct]);
        }
        c0 = c0n; c1 = c1n;
    }
    // O tile -> LDS (bf16)
    #pragma unroll
    for (int ct = 0; ct < 8; ++ct) {
        uint2v p0, p1;
        p0[0] = pk_bf(acc0[ct][0], acc0[ct][1]);
        p0[1] = pk_bf(acc0[ct][2], acc0[ct][3]);
        p1[0] = pk_bf(acc1[ct][0], acc1[ct][1]);
        p1[1] = pk_bf(acc1[ct][2], acc1[ct][3]);
        *(uint2v*)&Obf[w * 32 + l][ct * 16 + q * 4] = p0;
        *(uint2v*)&Obf[w * 32 + 16 + l][ct * 16 + q * 4] = p1;
    }
    __syncthreads();
    // epilogue: out = x + gamma*(Wv @ O + bv); wave handles its m-sub 32, all 256 cc
    const unsigned short* Wvf = (const unsigned short*)(ws + WVF_OFF);
    const float gam = gamma[0];
    bf16x8 bO0[4], bO1[4];
    #pragma unroll
    for (int ks = 0; ks < 4; ++ks) {
        bO0[ks] = *(const bf16x8*)&Obf[w * 32 + l][ks * 32 + q * 8];
        bO1[ks] = *(const bf16x8*)&Obf[w * 32 + 16 + l][ks * 32 + q * 8];
    }
    const int mg = blockIdx.x * 128 + w * 32 + l;
    const float* xb = x + b * (256 * 4096);
    float* ob = out + b * (256 * 4096);
    #pragma unroll
    for (int cct = 0; cct < 16; ++cct) {
        f32x4 f0 = {0.f, 0.f, 0.f, 0.f}, f1 = {0.f, 0.f, 0.f, 0.f};
        #pragma unroll
        for (int ks = 0; ks < 4; ++ks) {
            const bf16x8 aV = *(const bf16x8*)&Wvf[((cct * 4 + ks) * 64 + lane) * 8];
            f0 = mfma_bf16(aV, bO0[ks], f0);
            f1 = mfma_bf16(aV, bO1[ks], f1);
        }
        #pragma unroll
        for (int r = 0; r < 4; ++r) {
            const int cc = cct * 16 + q * 4 + r;
            const float bvc = bv[cc];
            ob[cc * 4096 + mg]      = xb[cc * 4096 + mg]      + gam * (f0[r] + bvc);
            ob[cc * 4096 + mg + 16] = xb[cc * 4096 + mg + 16] + gam * (f1[r] + bvc);
        }
    }
}

extern "C" void kernel_launch(void* const* d_in, const int* in_sizes, int n_in,
                              void* d_out, int out_size, void* d_ws, size_t ws_size,
                              hipStream_t stream) {
    const float* x   = (const float*)d_in[0];
    const float* wf  = (const float*)d_in[1];
    const float* bfv = (const float*)d_in[2];
    const float* wg  = (const float*)d_in[3];
    const float* bg  = (const float*)d_in[4];
    const float* wh  = (const float*)d_in[5];
    const float* bh  = (const float*)d_in[6];
    const float* wv  = (const float*)d_in[7];
    const float* bv  = (const float*)d_in[8];
    const float* gam = (const float*)d_in[9];
    float* out = (float*)d_out;
    unsigned char* ws = (unsigned char*)d_ws;
    (void)in_sizes; (void)n_in; (void)out_size; (void)ws_size;

    hipLaunchKernelGGL(k0_pack, dim3(321), dim3(256), 0, stream,
                       wf, bfv, wg, bg, wh, bh, wv, ws);
    hipLaunchKernelGGL(k1_proj, dim3(64, 8), dim3(256), 0, stream, x, ws);
    hipLaunchKernelGGL(k2_stats, dim3(16, 8, 4), dim3(256), 0, stream, ws);
    hipLaunchKernelGGL(k2b_inv, dim3(32), dim3(256), 0, stream, ws);
    hipLaunchKernelGGL(k3_attn, dim3(32, 8), dim3(256), 0, stream,
                       x, bv, gam, out, ws);
}